// Round 1
// baseline (130.098 us; speedup 1.0000x reference)
//
#include <hip/hip_runtime.h>
#include <math.h>

#define BM   64
#define BK   64
#define KDIM 256
#define LDSW 68   // BM + 4 pad: keeps 16B alignment for b128, breaks bank conflicts
#define HSW  65   // h-tile stride: (65*r + k) % 32 = (r+k)%32 -> 2-way (free) in epilogue dot

__global__ __launch_bounds__(256, 4)
void qc_fused(const float* __restrict__ x,
              const float* __restrict__ W1,
              const float* __restrict__ b1,
              const float* __restrict__ W2,
              const float* __restrict__ b2,
              const float* __restrict__ qw,
              float* __restrict__ out)
{
    __shared__ float smem[2 * BK * LDSW];   // xs | ws  (reused as hs | angs in epilogue)
    __shared__ float w2s[4 * 64];
    __shared__ float b1s[64];
    __shared__ float b2s[4];
    __shared__ float trig[2 * 4 * 4];       // [layer][qubit][{cy,sy,cz,sz}]

    float (*xs)[LDSW] = (float(*)[LDSW])smem;
    float (*ws)[LDSW] = (float(*)[LDSW])(smem + BK * LDSW);

    const int tid  = threadIdx.x;
    const int tx   = tid & 15;   // output-col group (4*tx .. 4*tx+3)
    const int ty   = tid >> 4;   // row group       (4*ty .. 4*ty+3)
    const int row0 = blockIdx.x * BM;

    // ---- one-time per-block setup ----
    w2s[tid] = W2[tid];                       // 256 = 4*64 exactly
    if (tid < 64) b1s[tid] = b1[tid];
    if (tid < 4)  b2s[tid] = b2[tid];
    if (tid < 8) {
        int l = tid >> 2, i = tid & 3;
        float wy = qw[(l * 4 + i) * 2 + 0];
        float wz = qw[(l * 4 + i) * 2 + 1];
        float sy, cy, sz, cz;
        sincosf(0.5f * wy, &sy, &cy);
        sincosf(0.5f * wz, &sz, &cz);
        trig[(l * 4 + i) * 4 + 0] = cy;
        trig[(l * 4 + i) * 4 + 1] = sy;
        trig[(l * 4 + i) * 4 + 2] = cz;
        trig[(l * 4 + i) * 4 + 3] = sz;
    }

    float acc[4][4] = {};

    const int lr = tid >> 4;   // 0..15 (row within load group)
    const int kq = tid & 15;   // 0..15 (float4 index along K)

    // ---- main GEMM1 loop: h_pre = x @ W1^T ----
    for (int kt = 0; kt < KDIM / BK; ++kt) {
        if (kt) __syncthreads();
        #pragma unroll
        for (int rr = 0; rr < 4; ++rr) {
            int r = rr * 16 + lr;            // 0..63, also W1 row index
            float4 xv = *(const float4*)(x  + (size_t)(row0 + r) * KDIM + kt * BK + kq * 4);
            float4 wv = *(const float4*)(W1 + (size_t)r          * KDIM + kt * BK + kq * 4);
            xs[kq * 4 + 0][r] = xv.x; xs[kq * 4 + 1][r] = xv.y;
            xs[kq * 4 + 2][r] = xv.z; xs[kq * 4 + 3][r] = xv.w;
            ws[kq * 4 + 0][r] = wv.x; ws[kq * 4 + 1][r] = wv.y;
            ws[kq * 4 + 2][r] = wv.z; ws[kq * 4 + 3][r] = wv.w;
        }
        __syncthreads();
        #pragma unroll 8
        for (int k = 0; k < BK; ++k) {
            float4 xa = *(const float4*)&xs[k][4 * ty];
            float4 wa = *(const float4*)&ws[k][4 * tx];
            float xr[4] = {xa.x, xa.y, xa.z, xa.w};
            float wc[4] = {wa.x, wa.y, wa.z, wa.w};
            #pragma unroll
            for (int i = 0; i < 4; ++i)
                #pragma unroll
                for (int j = 0; j < 4; ++j)
                    acc[i][j] = fmaf(xr[i], wc[j], acc[i][j]);
        }
    }
    __syncthreads();

    // ---- bias + relu -> hs (reuse xs region, stride 65) ----
    float* hsf = smem;
    #pragma unroll
    for (int i = 0; i < 4; ++i)
        #pragma unroll
        for (int j = 0; j < 4; ++j) {
            float v = acc[i][j] + b1s[4 * tx + j];
            hsf[(4 * ty + i) * HSW + (4 * tx + j)] = fmaxf(v, 0.0f);
        }
    __syncthreads();

    // ---- angles = tanh(h @ W2^T + b2): 256 threads = 64 rows x 4 outputs ----
    float* angs = smem + BK * LDSW;   // reuse ws region
    {
        int r = tid & 63, qi = tid >> 6;
        float s = b2s[qi];
        #pragma unroll 16
        for (int k = 0; k < 64; ++k)
            s = fmaf(hsf[r * HSW + k], w2s[qi * 64 + k], s);
        angs[r * 4 + qi] = tanhf(s);
    }
    __syncthreads();

    // ---- quantum circuit: one thread per row ----
    if (tid < 64) {
        float ca[4], sa[4];
        #pragma unroll
        for (int i = 0; i < 4; ++i) {
            float a = angs[tid * 4 + i];
            __sincosf(0.5f * a, &sa[i], &ca[i]);
        }
        // initial state: product of RY(angle)|0> = [c, s] per qubit (real)
        // index: idx = w0*8 + w1*4 + w2*2 + w3  (wire 0 is MSB)
        float re[16], im[16];
        #pragma unroll
        for (int idx = 0; idx < 16; ++idx) {
            re[idx] = (idx & 8 ? sa[0] : ca[0]) * (idx & 4 ? sa[1] : ca[1]) *
                      (idx & 2 ? sa[2] : ca[2]) * (idx & 1 ? sa[3] : ca[3]);
            im[idx] = 0.0f;
        }
        #pragma unroll
        for (int l = 0; l < 2; ++l) {
            #pragma unroll
            for (int i = 0; i < 4; ++i) {
                const float cy = trig[(l * 4 + i) * 4 + 0];
                const float sy = trig[(l * 4 + i) * 4 + 1];
                const float cz = trig[(l * 4 + i) * 4 + 2];
                const float sz = trig[(l * 4 + i) * 4 + 3];
                const int m = 8 >> i;
                // RY(wy) on wire i: a' = c*a - s*b ; b' = s*a + c*b
                #pragma unroll
                for (int idx = 0; idx < 16; ++idx) {
                    if (!(idx & m)) {
                        int j = idx | m;
                        float ar = re[idx], ai = im[idx], br = re[j], bi = im[j];
                        re[idx] = fmaf(cy, ar, -sy * br);
                        im[idx] = fmaf(cy, ai, -sy * bi);
                        re[j]   = fmaf(sy, ar,  cy * br);
                        im[j]   = fmaf(sy, ai,  cy * bi);
                    }
                }
                // RZ(wz) on wire i: bit0 *= (cz - i*sz), bit1 *= (cz + i*sz)
                #pragma unroll
                for (int idx = 0; idx < 16; ++idx) {
                    float sgn = (idx & m) ? sz : -sz;
                    float ar = re[idx], ai = im[idx];
                    re[idx] = fmaf(ar, cz, -ai * sgn);
                    im[idx] = fmaf(ar, sgn, ai * cz);
                }
            }
            // CNOT chain: (0,1),(1,2),(2,3),(3,0): swap (ctrl=1, tgt=0) <-> (ctrl=1, tgt=1)
            #pragma unroll
            for (int c = 0; c < 4; ++c) {
                int t  = (c + 1) & 3;
                int mc = 8 >> c, mt = 8 >> t;
                #pragma unroll
                for (int idx = 0; idx < 16; ++idx) {
                    if ((idx & mc) && !(idx & mt)) {
                        int j = idx | mt;
                        float tr = re[idx]; re[idx] = re[j]; re[j] = tr;
                        float ti = im[idx]; im[idx] = im[j]; im[j] = ti;
                    }
                }
            }
        }
        // <Z0> = sum_{w0=0} p - sum_{w0=1} p
        float z = 0.0f;
        #pragma unroll
        for (int idx = 0; idx < 16; ++idx) {
            float p = re[idx] * re[idx] + im[idx] * im[idx];
            z += (idx & 8) ? -p : p;
        }
        out[row0 + tid] = z;
    }
}

extern "C" void kernel_launch(void* const* d_in, const int* in_sizes, int n_in,
                              void* d_out, int out_size, void* d_ws, size_t ws_size,
                              hipStream_t stream) {
    const float* x   = (const float*)d_in[0];
    const float* W1  = (const float*)d_in[1];
    const float* b1  = (const float*)d_in[2];
    const float* W2  = (const float*)d_in[3];
    const float* b2  = (const float*)d_in[4];
    const float* qw  = (const float*)d_in[5];
    float* out = (float*)d_out;
    const int B = in_sizes[0] / KDIM;   // 65536
    qc_fused<<<B / BM, 256, 0, stream>>>(x, W1, b1, W2, b2, qw, out);
}

// Round 2
// 104.489 us; speedup vs baseline: 1.2451x; 1.2451x over previous
//
#include <hip/hip_runtime.h>
#include <math.h>

typedef _Float16 half8  __attribute__((ext_vector_type(8)));
typedef _Float16 half4v __attribute__((ext_vector_type(4)));
typedef float    float4v __attribute__((ext_vector_type(4)));

#define BM   128
#define KDIM 256
#define BKF  128     // K-chunk (floats/halves)
#define XSTR 136     // halves per LDS row = BKF + 8 pad; 272 B, 16B-aligned
#define HSW  65      // fp32 h-tile stride: (r+k)%32 -> 2-way (free)

__global__ __launch_bounds__(256, 2)
void qc_fused(const float* __restrict__ x,
              const float* __restrict__ W1,
              const float* __restrict__ b1,
              const float* __restrict__ W2,
              const float* __restrict__ b2,
              const float* __restrict__ qw,
              float* __restrict__ out)
{
    __shared__ _Float16 xh[BM * XSTR];   // 34816 B; reused as fp32 hs[128*65] later
    __shared__ _Float16 wh[64 * XSTR];   // 17408 B
    __shared__ float w2s[256];
    __shared__ float b1s[64];
    __shared__ float b2s[4];
    __shared__ float trig[32];           // [layer][qubit][{cy,sy,cz,sz}]

    const int tid  = threadIdx.x;
    const int lane = tid & 63;
    const int wv   = tid >> 6;           // wave 0..3 -> rows wv*32..wv*32+31
    const int m    = lane & 15;
    const int q    = lane >> 4;
    const int row0 = blockIdx.x * BM;

    // ---- one-time per-block setup (before first sync) ----
    w2s[tid] = W2[tid];                  // 4*64 = 256
    if (tid < 64) b1s[tid] = b1[tid];
    if (tid < 4)  b2s[tid] = b2[tid];
    if (tid < 8) {
        int l = tid >> 2, i = tid & 3;
        float wy = qw[(l * 4 + i) * 2 + 0];
        float wz = qw[(l * 4 + i) * 2 + 1];
        float sy, cy, sz, cz;
        sincosf(0.5f * wy, &sy, &cy);
        sincosf(0.5f * wz, &sz, &cz);
        trig[(l * 4 + i) * 4 + 0] = cy;
        trig[(l * 4 + i) * 4 + 1] = sy;
        trig[(l * 4 + i) * 4 + 2] = cz;
        trig[(l * 4 + i) * 4 + 3] = sz;
    }

    float4v acc[2][4] = {};              // 2 row-tiles x 4 col-tiles, fp32

    const int sr  = tid >> 3, skq = tid & 7;   // x staging: 32 rows x 8 k-quads
    const int wr  = tid >> 2, wkq = tid & 3;   // W staging: 64 rows x 4 k-quads

    for (int kc = 0; kc < KDIM; kc += BKF) {
        if (kc) __syncthreads();
        // ---- stage x chunk: 128 rows x 128 k, fp32 -> fp16 ----
        #pragma unroll
        for (int i = 0; i < 4; ++i) {
            #pragma unroll
            for (int j = 0; j < 4; ++j) {
                int row = sr + 32 * i;
                int kf  = 4 * skq + 32 * j;
                const float4v v = *(const float4v*)(x + (size_t)(row0 + row) * KDIM + kc + kf);
                half4v h;
                h[0] = (_Float16)v[0]; h[1] = (_Float16)v[1];
                h[2] = (_Float16)v[2]; h[3] = (_Float16)v[3];
                *(half4v*)&xh[row * XSTR + kf] = h;
            }
        }
        // ---- stage W1 chunk: 64 rows x 128 k ----
        #pragma unroll
        for (int j = 0; j < 8; ++j) {
            int kf = 4 * wkq + 16 * j;
            const float4v v = *(const float4v*)(W1 + (size_t)wr * KDIM + kc + kf);
            half4v h;
            h[0] = (_Float16)v[0]; h[1] = (_Float16)v[1];
            h[2] = (_Float16)v[2]; h[3] = (_Float16)v[3];
            *(half4v*)&wh[wr * XSTR + kf] = h;
        }
        __syncthreads();
        // ---- MFMA inner loop: 4 k-steps of 32 ----
        #pragma unroll
        for (int ks = 0; ks < 4; ++ks) {
            const int ko = ks * 32 + q * 8;
            half8 af0 = *(const half8*)&xh[(wv * 32 +      m) * XSTR + ko];
            half8 af1 = *(const half8*)&xh[(wv * 32 + 16 + m) * XSTR + ko];
            #pragma unroll
            for (int b = 0; b < 4; ++b) {
                half8 bf = *(const half8*)&wh[(16 * b + m) * XSTR + ko];
                acc[0][b] = __builtin_amdgcn_mfma_f32_16x16x32_f16(af0, bf, acc[0][b], 0, 0, 0);
                acc[1][b] = __builtin_amdgcn_mfma_f32_16x16x32_f16(af1, bf, acc[1][b], 0, 0, 0);
            }
        }
    }
    __syncthreads();

    // ---- epilogue: bias + relu -> hs (fp32, reuse xh region) ----
    float* hs = (float*)xh;
    #pragma unroll
    for (int a = 0; a < 2; ++a) {
        #pragma unroll
        for (int b = 0; b < 4; ++b) {
            #pragma unroll
            for (int i = 0; i < 4; ++i) {
                int row = wv * 32 + 16 * a + 4 * q + i;   // C/D: row = quad*4+reg
                int col = 16 * b + m;                     //      col = lane&15
                float v = acc[a][b][i] + b1s[col];
                hs[row * HSW + col] = fmaxf(v, 0.0f);
            }
        }
    }
    __syncthreads();

    // ---- GEMM2 + tanh + quantum circuit: one thread per row ----
    if (tid < BM) {
        const int r = tid;
        float s0 = b2s[0], s1 = b2s[1], s2 = b2s[2], s3 = b2s[3];
        #pragma unroll 8
        for (int k = 0; k < 64; ++k) {
            float hv = hs[r * HSW + k];       // (r+k)%32 -> 2-way, free
            s0 = fmaf(hv, w2s[0 * 64 + k], s0);   // w2s broadcast, free
            s1 = fmaf(hv, w2s[1 * 64 + k], s1);
            s2 = fmaf(hv, w2s[2 * 64 + k], s2);
            s3 = fmaf(hv, w2s[3 * 64 + k], s3);
        }
        float ang[4] = { tanhf(s0), tanhf(s1), tanhf(s2), tanhf(s3) };

        float ca[4], sa[4];
        #pragma unroll
        for (int i = 0; i < 4; ++i)
            __sincosf(0.5f * ang[i], &sa[i], &ca[i]);

        // state idx = w0*8 + w1*4 + w2*2 + w3
        float re[16], im[16];
        #pragma unroll
        for (int idx = 0; idx < 16; ++idx) {
            re[idx] = (idx & 8 ? sa[0] : ca[0]) * (idx & 4 ? sa[1] : ca[1]) *
                      (idx & 2 ? sa[2] : ca[2]) * (idx & 1 ? sa[3] : ca[3]);
            im[idx] = 0.0f;
        }
        #pragma unroll
        for (int l = 0; l < 2; ++l) {
            #pragma unroll
            for (int i = 0; i < 4; ++i) {
                const float cy = trig[(l * 4 + i) * 4 + 0];
                const float sy = trig[(l * 4 + i) * 4 + 1];
                const float cz = trig[(l * 4 + i) * 4 + 2];
                const float sz = trig[(l * 4 + i) * 4 + 3];
                const int mq = 8 >> i;
                #pragma unroll
                for (int idx = 0; idx < 16; ++idx) {
                    if (!(idx & mq)) {
                        int j = idx | mq;
                        float ar = re[idx], ai = im[idx], br = re[j], bi = im[j];
                        re[idx] = fmaf(cy, ar, -sy * br);
                        im[idx] = fmaf(cy, ai, -sy * bi);
                        re[j]   = fmaf(sy, ar,  cy * br);
                        im[j]   = fmaf(sy, ai,  cy * bi);
                    }
                }
                #pragma unroll
                for (int idx = 0; idx < 16; ++idx) {
                    float sgn = (idx & mq) ? sz : -sz;
                    float ar = re[idx], ai = im[idx];
                    re[idx] = fmaf(ar, cz, -ai * sgn);
                    im[idx] = fmaf(ar, sgn, ai * cz);
                }
            }
            #pragma unroll
            for (int c = 0; c < 4; ++c) {
                int t  = (c + 1) & 3;
                int mc = 8 >> c, mt = 8 >> t;
                #pragma unroll
                for (int idx = 0; idx < 16; ++idx) {
                    if ((idx & mc) && !(idx & mt)) {
                        int j = idx | mt;
                        float tr = re[idx]; re[idx] = re[j]; re[j] = tr;
                        float ti = im[idx]; im[idx] = im[j]; im[j] = ti;
                    }
                }
            }
        }
        float z = 0.0f;
        #pragma unroll
        for (int idx = 0; idx < 16; ++idx) {
            float p = re[idx] * re[idx] + im[idx] * im[idx];
            z += (idx & 8) ? -p : p;
        }
        out[row0 + r] = z;
    }
}

extern "C" void kernel_launch(void* const* d_in, const int* in_sizes, int n_in,
                              void* d_out, int out_size, void* d_ws, size_t ws_size,
                              hipStream_t stream) {
    const float* x  = (const float*)d_in[0];
    const float* W1 = (const float*)d_in[1];
    const float* b1 = (const float*)d_in[2];
    const float* W2 = (const float*)d_in[3];
    const float* b2 = (const float*)d_in[4];
    const float* qw = (const float*)d_in[5];
    float* out = (float*)d_out;
    const int B = in_sizes[0] / KDIM;   // 65536
    qc_fused<<<B / BM, 256, 0, stream>>>(x, W1, b1, W2, b2, qw, out);
}